// Round 12
// baseline (84.739 us; speedup 1.0000x reference)
//
#include <hip/hip_runtime.h>
#include <hip/hip_fp16.h>
#include <cstdint>
#include <cstddef>

// FastGRNN cell, MI355X fp16-MFMA, v12.
// prep:   weights f32->f16 into wb.
// stage1: 256 blocks x 512 thr. g0 (bid<128): x@W1^T, BM=128, N-split 2.
//         g1 (bid>=128): h@U1^T, BM=256, k-halves x N-split 2.
//         B staged via global_load_lds(16B) with pre-swizzled global source;
//         A reg-staged f32->f16 with matching XOR swizzle. One barrier/iter,
//         loads issued at iter top and drained at iter bottom (overlap compute).
// stage2: pre = [wx | uh0+uh1] @ [W2|U2]^T (K=512), same staging scheme,
//         fused sigmoid/tanh epilogue.

typedef _Float16 half8 __attribute__((ext_vector_type(8)));
typedef float f32x4 __attribute__((ext_vector_type(4)));

#define DIN 1024
#define DH 2048
#define RK 256
#define RBLD 768
// wb half-offsets
#define OFF_W1H 0
#define OFF_U1H 262144
#define OFF_W2H 786432
#define OFF_U2H 1310720

__device__ __forceinline__ half8 cvt8(const float4 a, const float4 b) {
  half8 h;
  h[0] = (_Float16)a.x; h[1] = (_Float16)a.y; h[2] = (_Float16)a.z; h[3] = (_Float16)a.w;
  h[4] = (_Float16)b.x; h[5] = (_Float16)b.y; h[6] = (_Float16)b.z; h[7] = (_Float16)b.w;
  return h;
}

// 16B global->LDS direct copy. LDS dest is wave-uniform base + lane*16.
__device__ __forceinline__ void gload16(const _Float16* g, _Float16* lds) {
  __builtin_amdgcn_global_load_lds(
      (const __attribute__((address_space(1))) unsigned*)g,
      (__attribute__((address_space(3))) unsigned*)lds, 16, 0, 0);
}

// ---------------- prep: weights f32 -> f16 ----------------------------------
__global__ __launch_bounds__(256)
void fgrnn_prep(const float* __restrict__ W1, const float* __restrict__ U1,
                const float* __restrict__ W2, const float* __restrict__ U2,
                _Float16* __restrict__ wb) {
  const int q = blockIdx.x * 256 + threadIdx.x;
  const float* src;
  int rel;
  if (q < 65536) { src = W1; rel = q; }
  else if (q < 196608) { src = U1; rel = q - 65536; }
  else if (q < 327680) { src = W2; rel = q - 196608; }
  else { src = U2; rel = q - 327680; }
  const float4 v = reinterpret_cast<const float4*>(src)[rel];
  union { _Float16 h[4]; uint2 u; } cv;
  cv.h[0] = (_Float16)v.x; cv.h[1] = (_Float16)v.y;
  cv.h[2] = (_Float16)v.z; cv.h[3] = (_Float16)v.w;
  reinterpret_cast<uint2*>(wb)[q] = cv.u;
}

// ---------------- stage 1 body: BM=64*MI, BN=128, K=1024, 16 iters ----------
// 512 thr = 8 waves (4 rows x 2 cols of wave-tiles); wave tile (MI*16)x64.
// B via gload_lds with pre-swizzled source; A via registers + cvt.
template <int MI>  // 2 -> BM=128 (x), 4 -> BM=256 (h)
__device__ __forceinline__ void s1_body(
    const float* __restrict__ A, const int KA, const int kbase,
    const _Float16* __restrict__ Bw, _Float16* __restrict__ rbuf,
    const int row0, const int colbase,
    _Float16* __restrict__ AsB, _Float16* __restrict__ BsB) {
  constexpr int ASTR = MI * 64 * 64;   // halves per A buffer

  const int tid = threadIdx.x;
  const int lane = tid & 63;
  const int wv = tid >> 6;
  const int wr = wv >> 1, wc = wv & 1;   // 4x2 wave grid
  const int sr = tid >> 3;               // 0..63
  const int sc = (tid & 7) * 8;

  f32x4 acc[MI][4];
#pragma unroll
  for (int i = 0; i < MI; ++i)
#pragma unroll
    for (int j = 0; j < 4; ++j) acc[i][j] = (f32x4){0.f, 0.f, 0.f, 0.f};

  float4 ra[MI][2];

  auto LOADA = [&](int it) {
    const int k0 = kbase + it * 64;
#pragma unroll
    for (int j = 0; j < MI; ++j) {
      const float* s = A + (size_t)(row0 + j * 64 + sr) * KA + k0 + sc;
      ra[j][0] = *reinterpret_cast<const float4*>(s);
      ra[j][1] = *reinterpret_cast<const float4*>(s + 4);
    }
  };
  auto GLOADB = [&](_Float16* bs, int it) {
    const int k0 = kbase + it * 64;
#pragma unroll
    for (int g = 0; g < 2; ++g) {
      const int rb = wv * 16 + g * 8;              // wave-uniform row base
      const int row = rb + (lane >> 3);            // 8 rows per gload
      const int ch = ((lane & 7) * 8) ^ ((row & 7) << 3);  // inverse swizzle
      gload16(Bw + (size_t)row * KA + k0 + ch, bs + rb * 64);
    }
  };
  auto STOREA = [&](_Float16* as) {
#pragma unroll
    for (int j = 0; j < MI; ++j) {
      const int r = j * 64 + sr;
      *reinterpret_cast<half8*>(&as[r * 64 + (sc ^ ((r & 7) << 3))]) =
          cvt8(ra[j][0], ra[j][1]);
    }
  };
  auto COMPUTE = [&](const _Float16* as, const _Float16* bs) {
#pragma unroll
    for (int kk = 0; kk < 64; kk += 32) {
      half8 af[MI], bf[4];
#pragma unroll
      for (int mi = 0; mi < MI; ++mi) {
        const int r = wr * (MI * 16) + mi * 16 + (lane & 15);
        af[mi] = *reinterpret_cast<const half8*>(
            &as[r * 64 + ((kk + 8 * (lane >> 4)) ^ ((r & 7) << 3))]);
      }
#pragma unroll
      for (int ni = 0; ni < 4; ++ni) {
        const int r = wc * 64 + ni * 16 + (lane & 15);
        bf[ni] = *reinterpret_cast<const half8*>(
            &bs[r * 64 + ((kk + 8 * (lane >> 4)) ^ ((r & 7) << 3))]);
      }
#pragma unroll
      for (int mi = 0; mi < MI; ++mi)
#pragma unroll
        for (int ni = 0; ni < 4; ++ni)
          acc[mi][ni] =
              __builtin_amdgcn_mfma_f32_16x16x32_f16(af[mi], bf[ni], acc[mi][ni], 0, 0, 0);
    }
  };

  _Float16* as0 = AsB;
  _Float16* as1 = AsB + ASTR;
  _Float16* bs0 = BsB;
  _Float16* bs1 = BsB + 128 * 64;

  // prologue: stage tile 0, full drain, barrier
  LOADA(0);
  GLOADB(bs0, 0);
  STOREA(as0);
  asm volatile("s_waitcnt vmcnt(0)" ::: "memory");
  asm volatile("s_waitcnt lgkmcnt(0)" ::: "memory");
  __builtin_amdgcn_s_barrier();
  __builtin_amdgcn_sched_barrier(0);

  int p = 0;
#pragma unroll 1
  for (int it = 0; it < 16; ++it) {
    const bool more = (it + 1 < 16);
    if (more) {
      LOADA(it + 1);                     // A first (compiler waits these at STOREA)
      GLOADB(p ? bs0 : bs1, it + 1);     // B gloads newest -> stay in flight
    }
    __builtin_amdgcn_s_setprio(1);
    COMPUTE(p ? as1 : as0, p ? bs1 : bs0);
    __builtin_amdgcn_s_setprio(0);
    if (more) STOREA(p ? as0 : as1);
    asm volatile("s_waitcnt vmcnt(0)" ::: "memory");   // next tile's B landed
    asm volatile("s_waitcnt lgkmcnt(0)" ::: "memory"); // my ds_writes done
    __builtin_amdgcn_s_barrier();
    __builtin_amdgcn_sched_barrier(0);
    p ^= 1;
  }

  // D layout (16x16 family): row = 4*(lane>>4)+e, col = lane&15.
#pragma unroll
  for (int mi = 0; mi < MI; ++mi)
#pragma unroll
    for (int ni = 0; ni < 4; ++ni)
#pragma unroll
      for (int e = 0; e < 4; ++e) {
        const int row = row0 + wr * (MI * 16) + mi * 16 + 4 * (lane >> 4) + e;
        const int col = colbase + wc * 64 + ni * 16 + (lane & 15);
        rbuf[(size_t)row * RBLD + col] = (_Float16)acc[mi][ni][e];
      }
}

__global__ __launch_bounds__(512)
void fgrnn_stage1(const float* __restrict__ x, const float* __restrict__ h,
                  const _Float16* __restrict__ wb, _Float16* __restrict__ rbuf) {
  __shared__ _Float16 As[2 * 256 * 64];   // 64 KB (g0 uses half)
  __shared__ _Float16 Bs[2 * 128 * 64];   // 32 KB
  const int bid = blockIdx.x;
  if (bid < 128) {
    const int mtile = bid >> 1;          // 0..63
    const int ncol = bid & 1;
    s1_body<2>(x, DIN, 0, wb + OFF_W1H + (size_t)(ncol * 128) * DIN, rbuf,
               mtile * 128, ncol * 128, As, Bs);
  } else {
    const int t = bid - 128;
    const int mtile = t >> 2;            // 0..31
    const int kp = (t >> 1) & 1;
    const int ncol = t & 1;
    s1_body<4>(h, DH, kp * 1024, wb + OFF_U1H + (size_t)(ncol * 128) * DH, rbuf,
               mtile * 256, 256 + kp * 256 + ncol * 128, As, Bs);
  }
}

// ---------------- stage 2: pre = [wx | uh0+uh1] @ [W2|U2]^T, K=512 ----------
// 2048 blocks x 256 thr. BM=64, BN=128, 8 iters; 4 waves 2x2, wave 32x64.
// Same staging scheme: B via gload_lds pre-swizzled, A (rbuf + panel add) regs.
__global__ __launch_bounds__(256)
void fgrnn_stage2(const _Float16* __restrict__ rbuf, const _Float16* __restrict__ wb,
                  const float* __restrict__ state,
                  const float* __restrict__ bg, const float* __restrict__ bu,
                  const float* __restrict__ zeta, const float* __restrict__ nu,
                  float* __restrict__ out) {
  const int bid = blockIdx.x;
  const int L = (bid & 7) * 256 + (bid >> 3);   // XCD swizzle: mtile-banded
  const int mtile = L >> 4;   // 0..127
  const int ntile = L & 15;   // 0..15
  const int row0 = mtile * 64;
  const int col0 = ntile * 128;
  const _Float16* W2h = wb + OFF_W2H;
  const _Float16* U2h = wb + OFF_U2H;

  __shared__ _Float16 As[2 * 64 * 64];    // 16 KB
  __shared__ _Float16 Bs[2 * 128 * 64];   // 32 KB

  const int tid = threadIdx.x;
  const int lane = tid & 63;
  const int wv = tid >> 6;
  const int wr = wv >> 1, wc = wv & 1;
  const int sr = tid >> 3;      // 0..31
  const int sc = (tid & 7) * 8;

  f32x4 acc[2][4];
#pragma unroll
  for (int i = 0; i < 2; ++i)
#pragma unroll
    for (int j = 0; j < 4; ++j) acc[i][j] = (f32x4){0.f, 0.f, 0.f, 0.f};

  half8 pa[2], pa2[2];

  auto LOADA = [&](int it) {
    const int k0 = it * 64;
    const bool iswx = (k0 < 256);
#pragma unroll
    for (int j = 0; j < 2; ++j) {
      const _Float16* p = rbuf + (size_t)(row0 + j * 32 + sr) * RBLD + k0 + sc;
      pa[j] = *reinterpret_cast<const half8*>(p);
      if (!iswx) pa2[j] = *reinterpret_cast<const half8*>(p + 256);  // uh1 panel
    }
  };
  auto GLOADB = [&](_Float16* bs, int it) {
    const int k0 = it * 64;
    const _Float16* Bh = (k0 < 256) ? W2h : U2h;
    const int kb = k0 & 255;
#pragma unroll
    for (int g = 0; g < 4; ++g) {
      const int rb = wv * 32 + g * 8;
      const int row = rb + (lane >> 3);
      const int ch = ((lane & 7) * 8) ^ ((row & 7) << 3);
      gload16(Bh + (size_t)(col0 + row) * RK + kb + ch, bs + rb * 64);
    }
  };
  auto STOREA = [&](_Float16* as, int it) {
    const int k0 = it * 64;
#pragma unroll
    for (int j = 0; j < 2; ++j) {
      half8 v = pa[j];
      if (k0 >= 256) v = v + pa2[j];   // uh = uh0 + uh1
      const int r = j * 32 + sr;
      *reinterpret_cast<half8*>(&as[r * 64 + (sc ^ ((r & 7) << 3))]) = v;
    }
  };
  auto COMPUTE = [&](const _Float16* as, const _Float16* bs) {
#pragma unroll
    for (int kk = 0; kk < 64; kk += 32) {
      half8 af[2], bf[4];
#pragma unroll
      for (int mi = 0; mi < 2; ++mi) {
        const int r = wr * 32 + mi * 16 + (lane & 15);
        af[mi] = *reinterpret_cast<const half8*>(
            &as[r * 64 + ((kk + 8 * (lane >> 4)) ^ ((r & 7) << 3))]);
      }
#pragma unroll
      for (int ni = 0; ni < 4; ++ni) {
        const int r = wc * 64 + ni * 16 + (lane & 15);
        bf[ni] = *reinterpret_cast<const half8*>(
            &bs[r * 64 + ((kk + 8 * (lane >> 4)) ^ ((r & 7) << 3))]);
      }
#pragma unroll
      for (int mi = 0; mi < 2; ++mi)
#pragma unroll
        for (int ni = 0; ni < 4; ++ni)
          acc[mi][ni] =
              __builtin_amdgcn_mfma_f32_16x16x32_f16(af[mi], bf[ni], acc[mi][ni], 0, 0, 0);
    }
  };

  _Float16* as0 = As;
  _Float16* as1 = As + 64 * 64;
  _Float16* bs0 = Bs;
  _Float16* bs1 = Bs + 128 * 64;

  LOADA(0);
  GLOADB(bs0, 0);
  STOREA(as0, 0);
  asm volatile("s_waitcnt vmcnt(0)" ::: "memory");
  asm volatile("s_waitcnt lgkmcnt(0)" ::: "memory");
  __builtin_amdgcn_s_barrier();
  __builtin_amdgcn_sched_barrier(0);

  int p = 0;
#pragma unroll 1
  for (int it = 0; it < 8; ++it) {
    const bool more = (it + 1 < 8);
    if (more) {
      LOADA(it + 1);
      GLOADB(p ? bs0 : bs1, it + 1);
    }
    __builtin_amdgcn_s_setprio(1);
    COMPUTE(p ? as1 : as0, p ? bs1 : bs0);
    __builtin_amdgcn_s_setprio(0);
    if (more) STOREA(p ? as0 : as1, it + 1);
    asm volatile("s_waitcnt vmcnt(0)" ::: "memory");
    asm volatile("s_waitcnt lgkmcnt(0)" ::: "memory");
    __builtin_amdgcn_s_barrier();
    __builtin_amdgcn_sched_barrier(0);
    p ^= 1;
  }

  // Fused epilogue (fast exp2/rcp; asymptotes correct)
  const float LOG2E = 1.44269504f;
  const float sz = __builtin_amdgcn_rcpf(1.f + __builtin_amdgcn_exp2f(-zeta[0] * LOG2E));
  const float sn = __builtin_amdgcn_rcpf(1.f + __builtin_amdgcn_exp2f(-nu[0] * LOG2E));
#pragma unroll
  for (int mi = 0; mi < 2; ++mi)
#pragma unroll
    for (int ni = 0; ni < 4; ++ni) {
      const int col = col0 + wc * 64 + ni * 16 + (lane & 15);
      const float bgc = bg[col];
      const float buc = bu[col];
#pragma unroll
      for (int e = 0; e < 4; ++e) {
        const int row = row0 + wr * 32 + mi * 16 + 4 * (lane >> 4) + e;
        const float pre = acc[mi][ni][e];
        const float zg =
            __builtin_amdgcn_rcpf(1.f + __builtin_amdgcn_exp2f(-(pre + bgc) * LOG2E));
        const float hc =
            1.f - 2.f * __builtin_amdgcn_rcpf(
                            1.f + __builtin_amdgcn_exp2f((pre + buc) * (2.f * LOG2E)));
        const float sv = state[(size_t)row * DH + col];
        out[(size_t)row * DH + col] = zg * sv + (sz * (1.f - zg) + sn) * hc;
      }
    }
}

extern "C" void kernel_launch(void* const* d_in, const int* in_sizes, int n_in,
                              void* d_out, int out_size, void* d_ws, size_t ws_size,
                              hipStream_t stream) {
  const float* input = (const float*)d_in[0];
  const float* state = (const float*)d_in[1];
  const float* W1 = (const float*)d_in[2];
  const float* W2 = (const float*)d_in[3];
  const float* U1 = (const float*)d_in[4];
  const float* U2 = (const float*)d_in[5];
  const float* bg = (const float*)d_in[6];
  const float* bu = (const float*)d_in[7];
  const float* zeta = (const float*)d_in[8];
  const float* nu = (const float*)d_in[9];
  float* out = (float*)d_out;

  _Float16* rbuf = (_Float16*)d_ws;                     // 8192*768*2 = 12.6 MB
  _Float16* wb = rbuf + (size_t)8192 * RBLD;            // +3.67 MB f16 weights

  fgrnn_prep<<<1792, 256, 0, stream>>>(W1, U1, W2, U2, wb);
  fgrnn_stage1<<<256, 512, 0, stream>>>(input, state, wb, rbuf);
  fgrnn_stage2<<<2048, 256, 0, stream>>>(rbuf, wb, state, bg, bu, zeta, nu, out);
}